// Round 12
// baseline (477.383 us; speedup 1.0000x reference)
//
#include <hip/hip_runtime.h>
#include <math.h>

typedef __bf16 bf16;
typedef __bf16 bf16x8 __attribute__((ext_vector_type(8)));
typedef __bf16 bf16x4 __attribute__((ext_vector_type(4)));
typedef float f32x4 __attribute__((ext_vector_type(4)));
typedef unsigned int u32x4 __attribute__((ext_vector_type(4)));

// ---- async global->LDS, 16B per lane. LDS dest = wave-uniform base (+lane*16 implicit).
__device__ inline void gload16(const void* g, void* l) {
  typedef __attribute__((address_space(1))) const unsigned int guint;
  typedef __attribute__((address_space(3))) unsigned int luint;
  __builtin_amdgcn_global_load_lds((guint*)g, (luint*)l, 16, 0, 0);
}

// ================= 256x256 8-phase GEMM (r8-proven schedule, frozen). 512 threads =
// 8 waves (2Mx4N), per-wave output 128x64 (acc[8][4]), mfma 16x16x32 bf16.
// LDS ring of 4 slots per operand (4 x 8192 bf16 = 16KB each, 64KB/operand).
// 1-D grid + XCD placement (block i -> XCD i%8): c=i&7, s=i>>3; zb=c>>zshift;
// m_tile=(c&((1<<zshift)-1))*mper + (s>>nshift); n_tile=s&((1<<nshift)-1).
// Counted-vmcnt: stage(H) at phase H-5; waits vmcnt(4) at p0 / vmcnt(6) at p3
// (exact counts at tail). Epilogue: per-wave LDS repack (16B-chunk XOR swizzle)
// -> 16 coalesced dwordx4 stores per thread.
// C[m][n] = op(scale * sum_k A[m][k]*B[n][k] + bias); C row stride = ldc.
// bias2: used when zb==1 (merged proj launch). A2: A base for zb>=4 (split attnb).
template<int BIAS_MODE, bool GELU>
__global__ __launch_bounds__(512, 2)
void bgemm8_k(const bf16* __restrict__ A, const bf16* __restrict__ A2,
              const bf16* __restrict__ B,
              const float* __restrict__ bias, const float* __restrict__ bias2,
              bf16* __restrict__ Cout, int ldc, int K,
              long sAb, long sBb, long sCb, float scale,
              int nshift, int zshift, int mper)
{
  __shared__ __align__(16) char smem[131072];
  bf16* As = (bf16*)smem;              // [4 slots][256][32] bf16, slot stride 8192 elems
  bf16* Bs = (bf16*)(smem + 65536);

  const int t    = threadIdx.x;
  const int i    = blockIdx.x;
  const int c    = i & 7;              // XCD (dispatch round-robin)
  const int s    = i >> 3;             // slot within XCD
  const int zb   = c >> zshift;
  const int mchunk = c & ((1 << zshift) - 1);
  const int m_tile = mchunk * mper + (s >> nshift);
  const int n_tile = s & ((1 << nshift) - 1);
  const int m0   = m_tile << 8;
  const int n0   = n_tile << 8;

  const float* bp = (BIAS_MODE && bias2 && zb) ? bias2 : bias;

  const int wave = t >> 6;
  const int lane = t & 63;
  const int wm = wave >> 2;          // 0..1 -> rows wm*128..+128
  const int wn = wave & 3;           // 0..3 -> cols wn*64..+64
  const int fr = lane & 15;
  const int fg = lane >> 4;          // 0..3

  // ---- staging constants (2 issues per thread per half-slab)
  const bf16* Aroot = (A2 && zb >= 4) ? A2 : A;
  const int   za    = (A2 && zb >= 4) ? zb - 4 : zb;
  const bf16* Abase = Aroot + (size_t)za * sAb + (size_t)m0 * K;
  const bf16* Bbase = B + (size_t)zb * sBb + (size_t)n0 * K;
  size_t gOff[2];
  int    ldsOff[2];
#pragma unroll
  for (int j = 0; j < 2; ++j) {
    const int L   = j * 8192 + t * 16;   // byte offset within 16KB slab-part
    const int row = L >> 6;              // 0..255
    const int gp  = (L >> 4) & 3;        // linear LDS granule
    const int g   = gp ^ ((row >> 1) & 3);   // pre-swizzled global granule
    gOff[j]   = (size_t)row * K + (size_t)g * 8;
    ldsOff[j] = j * 4096 + wave * 512;   // elements; wave-uniform; HW adds lane*16B
  }
  const int HMAX = (K >> 5) * 2;   // 2 half-slabs per 32-wide slab

  auto stage = [&](int H) {
    if (H >= HMAX) return;
    const int sl   = H >> 1;
    const int slot = sl & 3;
    const size_t kof = (size_t)sl * 32;
    if ((H & 1) == 0) {
      gload16(Abase + kof + gOff[0], As + slot * 8192 + ldsOff[0]);
      gload16(Abase + kof + gOff[1], As + slot * 8192 + ldsOff[1]);
    } else {
      gload16(Bbase + kof + gOff[0], Bs + slot * 8192 + ldsOff[0]);
      gload16(Bbase + kof + gOff[1], Bs + slot * 8192 + ldsOff[1]);
    }
  };

  // ---- fragment read offsets (swizzled): row base multiple of 16 -> xor is (fr>>1)&3
  const int xsw  = (fg ^ ((fr >> 1) & 3)) * 8;
  const int aoff = (wm * 128 + fr) * 32 + xsw;
  const int boff = (wn * 64 + fr) * 32 + xsw;

  f32x4 acc[8][4] = {};
  const int T = K >> 6;   // K-tiles of 64

  // prologue: A(s0),B(s0),A(s1),B(s1),A(s2); need slab 0 (H<=1) -> vmcnt(6)
  stage(0); stage(1); stage(2); stage(3); stage(4);
  asm volatile("s_waitcnt vmcnt(6)" ::: "memory");
  __builtin_amdgcn_s_barrier();

  for (int tt = 0; tt < T; ++tt) {
#pragma unroll
    for (int p = 0; p < 4; ++p) {
      const int kk   = p & 1;        // k-half of this K-tile (32-slab)
      const int oh   = p >> 1;       // output half (mi 0-3 / 4-7)
      const int slot = (2 * tt + kk) & 3;
      bf16x8 af[4], bfv[4];
#pragma unroll
      for (int i2 = 0; i2 < 4; ++i2)
        af[i2]  = *(const bf16x8*)(As + slot * 8192 + aoff + (oh * 4 + i2) * 512);
#pragma unroll
      for (int i2 = 0; i2 < 4; ++i2)
        bfv[i2] = *(const bf16x8*)(Bs + slot * 8192 + boff + i2 * 512);
      stage(4 * tt + p + 5);         // one half-slab, 5 phases ahead of first use
      __builtin_amdgcn_s_barrier();
      __builtin_amdgcn_s_setprio(1);
#pragma unroll
      for (int mi = 0; mi < 4; ++mi)
#pragma unroll
        for (int ni = 0; ni < 4; ++ni)
          acc[oh * 4 + mi][ni] =
            __builtin_amdgcn_mfma_f32_16x16x32_bf16(af[mi], bfv[ni], acc[oh * 4 + mi][ni], 0, 0, 0);
      __builtin_amdgcn_s_setprio(0);
      if (p == 0) {                   // publish slab 2tt+1 for p1 reads
        if (tt == T - 1) asm volatile("s_waitcnt vmcnt(0)" ::: "memory");
        else             asm volatile("s_waitcnt vmcnt(4)" ::: "memory");
      }
      if (p == 3) {                   // publish slab 2tt+2 for next tile's p0 reads
        if (tt < T - 2)       asm volatile("s_waitcnt vmcnt(6)" ::: "memory");
        else if (tt == T - 2) asm volatile("s_waitcnt vmcnt(4)" ::: "memory");
      }
      __builtin_amdgcn_s_barrier();
    }
  }

  // ---- epilogue: per-wave 16KB LDS repack, 16B-chunk XOR swizzle.
  bf16* wbuf = (bf16*)(smem + wave * 16384);   // [128 rows][128 bytes]
#pragma unroll
  for (int mi = 0; mi < 8; ++mi) {
#pragma unroll
    for (int ni = 0; ni < 4; ++ni) {
      const int col = n0 + wn * 64 + ni * 16 + fr;
#pragma unroll
      for (int i2 = 0; i2 < 4; ++i2) {
        const int r = mi * 16 + fg * 4 + i2;    // local row 0..127
        float v = acc[mi][ni][i2] * scale;
        if constexpr (BIAS_MODE == 1) v += bp[col];
        if constexpr (BIAS_MODE == 2) v += bp[m0 + wm * 128 + r];
        if constexpr (GELU) v = 0.5f * v * (1.0f + erff(v * 0.70710678118f));
        const int cb = ni * 32 + fr * 2;        // byte col 0..126
        *(bf16*)((char*)wbuf + r * 128 + (cb ^ ((r & 7) << 4))) = (bf16)v;
      }
    }
  }
  __syncthreads();   // repack writes visible before readback
  const int rowbase = m0 + wm * 128;
  const int colbase = n0 + wn * 64;
#pragma unroll
  for (int j = 0; j < 16; ++j) {
    const int r  = j * 8 + (lane >> 3);
    const int cg = lane & 7;                    // global 16B chunk within 128B row
    bf16x8 val = *(const bf16x8*)((char*)wbuf + r * 128 + ((cg << 4) ^ ((r & 7) << 4)));
    *(bf16x8*)(Cout + (size_t)zb * sCb + (size_t)(rowbase + r) * ldc + colbase + cg * 8) = val;
  }
}

// ---------------- pre1: z=0 weight transpose (all 4 via x>>8); z=1 conv Q; z=2 conv K
__global__ __launch_bounds__(256)
void pre1_k(const float* __restrict__ W0, const float* __restrict__ W1,
            const float* __restrict__ W2, const float* __restrict__ W3,
            bf16* __restrict__ wts,
            const float* __restrict__ Q, const float* __restrict__ Kin,
            bf16* __restrict__ Qb, bf16* __restrict__ Kb, long n8)
{
  __shared__ __align__(16) char sb[64 * 72 * 2];
  const int t = threadIdx.x;
  if (blockIdx.z == 0) {
    const float* Ws[4] = {W0, W1, W2, W3};
    const int wsel = blockIdx.x >> 8;
    const float* W = Ws[wsel];
    bf16* o = wts + (size_t)wsel * (1024 * 1024);
    const int c0 = (blockIdx.x & 15) * 64;
    const int r0 = ((blockIdx.x >> 4) & 15) * 64;
    bf16 (*tile)[72] = (bf16(*)[72])sb;
    {
      const int rr = t >> 2;
      const int cc = (t & 3) * 16;
      const float* src = W + (size_t)(r0 + rr) * 1024 + c0 + cc;
#pragma unroll
      for (int j = 0; j < 16; j += 4) {
        f32x4 v = __builtin_nontemporal_load((const f32x4*)(src + j));
#pragma unroll
        for (int i = 0; i < 4; ++i) tile[cc + j + i][rr] = (bf16)v[i];
      }
    }
    __syncthreads();
    {
      const int nr = t >> 2;
      const int kc = (t & 3) * 16;
      bf16* dst = o + (size_t)(c0 + nr) * 1024 + r0 + kc;
      *(bf16x8*)dst       = *(const bf16x8*)&tile[nr][kc];
      *(bf16x8*)(dst + 8) = *(const bf16x8*)&tile[nr][kc + 8];
    }
  } else {
    const float* in = (blockIdx.z == 1) ? Q : Kin;
    bf16* out = (blockIdx.z == 1) ? Qb : Kb;
    for (long i = blockIdx.x * 256 + t; i < n8; i += (long)gridDim.x * 256) {
      f32x4 a = __builtin_nontemporal_load((const f32x4*)(in + i * 8));
      f32x4 b = __builtin_nontemporal_load((const f32x4*)(in + i * 8 + 4));
      bf16x8 o;
#pragma unroll
      for (int j = 0; j < 4; ++j) { o[j] = (bf16)a[j]; o[4 + j] = (bf16)b[j]; }
      *(bf16x8*)(out + i * 8) = o;
    }
  }
}

// ---------------- pre2: z<8 mask transpose+BITPACK batch z; z=8 conv V
// (separate dispatch AFTER projections: mTb overwrites Qb, Vb overwrites Kb)
__global__ __launch_bounds__(256)
void pre2_k(const unsigned int* __restrict__ mask, unsigned char* __restrict__ mTb,
            const float* __restrict__ V, bf16* __restrict__ Vb, long n8)
{
  __shared__ __align__(16) char sb[64 * 72 * 2];
  const int t = threadIdx.x;
  if (blockIdx.z < 8) {
    const int b  = blockIdx.z;
    const int k0 = (blockIdx.x & 31) * 64;
    const int q0 = (blockIdx.x >> 5) * 64;
    signed char (*tile)[65] = (signed char(*)[65])sb;
    {
      const int iq = t >> 2;
      const int ic = (t & 3) * 16;
      const unsigned int* src = mask + ((size_t)b * 2048 + q0 + iq) * 2048 + k0 + ic;
#pragma unroll
      for (int j = 0; j < 16; j += 4) {
        u32x4 v = __builtin_nontemporal_load((const u32x4*)(src + j));
#pragma unroll
        for (int i = 0; i < 4; ++i) tile[ic + j + i][iq] = (signed char)v[i];
      }
    }
    __syncthreads();
    {
      const int ik = t >> 2;             // k within tile 0..63
      const int iq = (t & 3) * 16;       // q start 0/16/32/48
      unsigned int bits = 0;
#pragma unroll
      for (int j = 0; j < 16; ++j) bits |= (unsigned int)(tile[ik][iq + j] & 1) << j;
      *(unsigned short*)(mTb + ((size_t)b * 2048 + k0 + ik) * 256 + ((q0 + iq) >> 3)) =
          (unsigned short)bits;
    }
  } else {
    for (long i = blockIdx.x * 256 + t; i < n8; i += (long)gridDim.x * 256) {
      f32x4 a = __builtin_nontemporal_load((const f32x4*)(V + i * 8));
      f32x4 b = __builtin_nontemporal_load((const f32x4*)(V + i * 8 + 4));
      bf16x8 o;
#pragma unroll
      for (int j = 0; j < 4; ++j) { o[j] = (bf16)a[j]; o[4 + j] = (bf16)b[j]; }
      *(bf16x8*)(Vb + i * 8) = o;
    }
  }
}

// ---------------- row softmax, XCD-pinned: block i -> batch i%8 (same XCD that
// produced this batch's scores in QKT and consumes attnb in PV), row i/8.
// Reads bf16 scores (first 4KB of 8KB row slot) + bitpacked mask; writes f32 attn
// (NT, in slot) + bf16 attnb (normal stores -> stays in XCD L2 for PV).
__global__ __launch_bounds__(256)
void softmax_rows_k(float* __restrict__ P, const unsigned char* __restrict__ mTb,
                    bf16* __restrict__ Pb0, bf16* __restrict__ Pb1)
{
  const int b  = blockIdx.x & 7;
  const int rw = blockIdx.x >> 3;
  const size_t r = (size_t)b * 2048 + rw;
  char* slot = (char*)P + r * 8192;
  const bf16* pin = (const bf16*)slot;
  float* pout = (float*)slot;
  bf16* pb = (b < 4) ? (Pb0 + ((size_t)b * 2048 + rw) * 2048)
                     : (Pb1 + ((size_t)(b - 4) * 2048 + rw) * 2048);
  const int t = threadIdx.x;
  const int wave = t >> 6, lane = t & 63;
  bf16x8 raw = *(const bf16x8*)(pin + t * 8);
  const unsigned int mbyte = mTb[r * 256 + t];   // 8 q-bits for this thread
  float v[8];
#pragma unroll
  for (int j = 0; j < 8; ++j)
    v[j] = (float)raw[j] + (((mbyte >> j) & 1) ? -1e9f : 0.0f);
  float m = -3e38f;
#pragma unroll
  for (int j = 0; j < 8; ++j) m = fmaxf(m, v[j]);
#pragma unroll
  for (int off = 32; off; off >>= 1) m = fmaxf(m, __shfl_xor(m, off));
  __shared__ float red[8];
  if (lane == 0) red[wave] = m;
  __syncthreads();
  m = fmaxf(fmaxf(red[0], red[1]), fmaxf(red[2], red[3]));
  float s = 0.0f;
#pragma unroll
  for (int j = 0; j < 8; ++j) { v[j] = __expf(v[j] - m); s += v[j]; }
#pragma unroll
  for (int off = 32; off; off >>= 1) s += __shfl_xor(s, off);
  if (lane == 0) red[4 + wave] = s;
  __syncthreads();
  s = red[4] + red[5] + red[6] + red[7];
  const float inv = 1.0f / s;
  f32x4 o0, o1;
  bf16x8 ob;
#pragma unroll
  for (int j = 0; j < 4; ++j) {
    o0[j] = v[j] * inv; o1[j] = v[4 + j] * inv;
    ob[j] = (bf16)o0[j]; ob[4 + j] = (bf16)o1[j];
  }
  __builtin_nontemporal_store(o0, (f32x4*)(pout + t * 8));
  __builtin_nontemporal_store(o1, (f32x4*)(pout + t * 8 + 4));
  *(bf16x8*)(pb + t * 8) = ob;
}

// ---------------- LayerNorm over 1024, bf16 input, XCD-pinned (block i -> row
// (i%8)*2048 + i/8, matching gelu's batch->XCD placement for warm g reads).
__global__ __launch_bounds__(256)
void ln_k(const bf16* __restrict__ g, const float* __restrict__ gamma,
          const float* __restrict__ beta, float* __restrict__ out)
{
  const size_t r = (size_t)(blockIdx.x & 7) * 2048 + (blockIdx.x >> 3);
  const bf16* p = g + r * 1024;
  const int t = threadIdx.x;
  const int wave = t >> 6, lane = t & 63;
  bf16x4 raw = *(const bf16x4*)(p + t * 4);
  f32x4 v;
#pragma unroll
  for (int j = 0; j < 4; ++j) v[j] = (float)raw[j];
  float s = v[0] + v[1] + v[2] + v[3];
  float q = v[0]*v[0] + v[1]*v[1] + v[2]*v[2] + v[3]*v[3];
#pragma unroll
  for (int off = 32; off; off >>= 1) { s += __shfl_xor(s, off); q += __shfl_xor(q, off); }
  __shared__ float red[16];
  if (lane == 0) { red[wave] = s; red[8 + wave] = q; }
  __syncthreads();
  s = red[0] + red[1] + red[2] + red[3];
  q = red[8] + red[9] + red[10] + red[11];
  const float mu   = s * (1.0f / 1024.0f);
  const float var  = q * (1.0f / 1024.0f) - mu * mu;
  const float rstd = rsqrtf(var + 1e-5f);
  f32x4 gm = *(const f32x4*)(gamma + t * 4);
  f32x4 bt = *(const f32x4*)(beta + t * 4);
  f32x4 o;
#pragma unroll
  for (int j = 0; j < 4; ++j) o[j] = (v[j] - mu) * rstd * gm[j] + bt[j];
  __builtin_nontemporal_store(o, (f32x4*)(out + r * 1024 + t * 4));
}

extern "C" void kernel_launch(void* const* d_in, const int* in_sizes, int n_in,
                              void* d_out, int out_size, void* d_ws, size_t ws_size,
                              hipStream_t stream)
{
  const float* Q     = (const float*)d_in[0];
  const float* Kin   = (const float*)d_in[1];
  const float* V     = (const float*)d_in[2];
  const unsigned int* mask = (const unsigned int*)d_in[3];
  const float* Wq    = (const float*)d_in[4];
  const float* bq    = (const float*)d_in[5];
  const float* Wk    = (const float*)d_in[6];
  const float* bk    = (const float*)d_in[7];
  const float* Wv    = (const float*)d_in[8];
  const float* bv    = (const float*)d_in[9];
  const float* Wo    = (const float*)d_in[10];
  const float* bo    = (const float*)d_in[11];
  const float* gamma = (const float*)d_in[12];
  const float* beta  = (const float*)d_in[13];

  float* outCtx  = (float*)d_out;                      // [8,2048,1024]
  float* outAttn = outCtx + (size_t)8 * 2048 * 1024;   // [8,2048,2048] (k,q); 8KB row slots

  // workspace (MiB offsets), peak 136 MiB; per-region timeline:
  // [0,8)    wts (whole run)
  // [8,40)   qp (proj->QKT)   -> wvT (wvT->PV)
  // [40,72)  kp (proj->QKT)   -> attnb b0-3 (softmax->PV) -> g (gelu->ln)
  // [72,104) Qb (pre1->proj)  -> mTb 4MB (pre2->softmax)  -> ctx (PV->gelu)
  // [104,136) Kb (pre1->proj) -> Vb (pre2->wvT)           -> attnb b4-7 (softmax->PV)
  char* ws = (char*)d_ws;
  const size_t MB = 1048576;
  bf16*          wts   = (bf16*)(ws + 0 * MB);
  bf16*          qp    = (bf16*)(ws + 8 * MB);
  bf16*          kp    = (bf16*)(ws + 40 * MB);
  bf16*          Qb    = (bf16*)(ws + 72 * MB);
  bf16*          Kb    = (bf16*)(ws + 104 * MB);
  unsigned char* mTb   = (unsigned char*)(ws + 72 * MB);
  bf16*          Vb    = (bf16*)(ws + 104 * MB);
  bf16*          wvT   = (bf16*)(ws + 8 * MB);
  bf16*          attnb0= (bf16*)(ws + 40 * MB);
  bf16*          attnb1= (bf16*)(ws + 104 * MB);
  bf16*          ctx   = (bf16*)(ws + 72 * MB);
  bf16*          g     = (bf16*)(ws + 40 * MB);
  bf16* Wvt = wts + 2 * 1024 * 1024;
  bf16* Wot = wts + 3 * 1024 * 1024;

  const dim3 blk(256);
  const dim3 blk8(512);
  const long n8 = (long)16384 * 1024 / 8;

  // 1. pre1: weights->bf16 transposed (z=0), Q->bf16 (z=1), K->bf16 (z=2)
  pre1_k<<<dim3(1024, 1, 3), blk, 0, stream>>>(Wq, Wk, Wv, Wo, wts, Q, Kin, Qb, Kb, n8);
  // 2. merged projections (512 blocks): XCD c -> z=c>>2, m-chunk c&3 (16 tiles), 4 n-tiles
  bgemm8_k<1, false><<<dim3(512), blk8, 0, stream>>>(
      Qb, nullptr, wts, bq, bk, qp, 1024, 1024,
      16777216, 1048576, 16777216, 1.0f, 2, 2, 16);
  // 3. pre2 (AFTER projections — mTb/Vb overwrite Qb/Kb): mask bitpack (z<8), V (z=8)
  pre2_k<<<dim3(1024, 1, 9), blk, 0, stream>>>(mask, mTb, V, Vb, n8);
  // 4. QKT (512 blocks): XCD c -> batch c; 8x8 tiles; scores bf16 (ldc=4096)
  bgemm8_k<0, false><<<dim3(512), blk8, 0, stream>>>(
      kp, nullptr, qp, nullptr, nullptr, (bf16*)outAttn, 4096, 1024,
      (long)2048 * 1024, (long)2048 * 1024, (long)2048 * 4096, 0.03125f, 3, 0, 8);
  // 5. wvT (256 blocks): XCD c -> batch c; 4 m-tiles x 8 n-tiles
  bgemm8_k<2, false><<<dim3(256), blk8, 0, stream>>>(
      Wvt, nullptr, Vb, bv, nullptr, wvT, 2048, 1024,
      0, (long)2048 * 1024, (long)1024 * 2048, 1.0f, 3, 0, 4);
  // 6. softmax (XCD-pinned rows): scores + mask bits -> f32 attn (NT) + bf16 attnb
  softmax_rows_k<<<dim3(16384), blk, 0, stream>>>(outAttn, mTb, attnb0, attnb1);
  // 7. PV (256 blocks): XCD c -> batch c; 8 m-tiles x 4 n-tiles
  bgemm8_k<0, false><<<dim3(256), blk8, 0, stream>>>(
      attnb0, attnb1, wvT, nullptr, nullptr, ctx, 1024, 2048,
      (long)2048 * 2048, (long)1024 * 2048, (long)2048 * 1024, 1.0f, 2, 0, 8);
  // 8. gelu (256 blocks): XCD c -> m-chunk c (= batch c rows), 4 n-tiles
  bgemm8_k<1, true><<<dim3(256), blk8, 0, stream>>>(
      ctx, nullptr, Wot, bo, nullptr, g, 1024, 1024,
      0, 0, 0, 1.0f, 2, 3, 8);
  // 9. LayerNorm (XCD-pinned rows) -> context output
  ln_k<<<dim3(16384), blk, 0, stream>>>(g, gamma, beta, outCtx);
}

// Round 13
// 465.855 us; speedup vs baseline: 1.0247x; 1.0247x over previous
//
#include <hip/hip_runtime.h>
#include <math.h>

typedef __bf16 bf16;
typedef __bf16 bf16x8 __attribute__((ext_vector_type(8)));
typedef __bf16 bf16x4 __attribute__((ext_vector_type(4)));
typedef float f32x4 __attribute__((ext_vector_type(4)));
typedef unsigned int u32x4 __attribute__((ext_vector_type(4)));

// ---- async global->LDS, 16B per lane. LDS dest = wave-uniform base (+lane*16 implicit).
__device__ inline void gload16(const void* g, void* l) {
  typedef __attribute__((address_space(1))) const unsigned int guint;
  typedef __attribute__((address_space(3))) unsigned int luint;
  __builtin_amdgcn_global_load_lds((guint*)g, (luint*)l, 16, 0, 0);
}

// ================= 256x256 8-phase GEMM (r8-proven schedule, frozen). 512 threads =
// 8 waves (2Mx4N), per-wave output 128x64 (acc[8][4]), mfma 16x16x32 bf16.
// LDS ring of 4 slots per operand (4 x 8192 bf16 = 16KB each, 64KB/operand).
// 1-D grid + XCD placement (block i -> XCD i%8): c=i&7, s=i>>3; zb=c>>zshift;
// m_tile=(c&((1<<zshift)-1))*mper + (s>>nshift); n_tile=s&((1<<nshift)-1).
// Counted-vmcnt: stage(H) at phase H-5; waits vmcnt(4) at p0 / vmcnt(6) at p3
// (exact counts at tail; PV's extra stores only make waits stricter - safe).
// Epilogue: per-wave LDS repack (16B-chunk XOR swizzle) -> 16 coalesced dwordx4.
// C[m][n] = op(scale * sum_k A[m][k]*B[n][k] + bias); C row stride = ldc.
// bias2: used when zb==1 (merged proj launch). A2: A base for zb>=4 (split attnb).
// PV_ATTN: PV also emits f32 attn = upcast of its A-fragments (attnb). Each
// element stored exactly once: wn==0 waves only, n_tile t stores K-tiles
// [8t,8t+8) (T=32, 4 n-tiles). Fragment af[i2] elem e = A[row][sl*32+fg*8+e]
// (staging pre-swizzle makes LDS granule fg hold global granule fg when the
// read swizzle key (fr>>1)&3 is applied - same key both sides).
template<int BIAS_MODE, bool GELU, bool PV_ATTN>
__global__ __launch_bounds__(512, 2)
void bgemm8_k(const bf16* __restrict__ A, const bf16* __restrict__ A2,
              const bf16* __restrict__ B,
              const float* __restrict__ bias, const float* __restrict__ bias2,
              bf16* __restrict__ Cout, int ldc, int K,
              long sAb, long sBb, long sCb, float scale,
              int nshift, int zshift, int mper,
              float* __restrict__ attnF, long sFb)
{
  __shared__ __align__(16) char smem[131072];
  bf16* As = (bf16*)smem;              // [4 slots][256][32] bf16, slot stride 8192 elems
  bf16* Bs = (bf16*)(smem + 65536);

  const int t    = threadIdx.x;
  const int i    = blockIdx.x;
  const int c    = i & 7;              // XCD (dispatch round-robin)
  const int s    = i >> 3;             // slot within XCD
  const int zb   = c >> zshift;
  const int mchunk = c & ((1 << zshift) - 1);
  const int m_tile = mchunk * mper + (s >> nshift);
  const int n_tile = s & ((1 << nshift) - 1);
  const int m0   = m_tile << 8;
  const int n0   = n_tile << 8;

  const float* bp = (BIAS_MODE && bias2 && zb) ? bias2 : bias;

  const int wave = t >> 6;
  const int lane = t & 63;
  const int wm = wave >> 2;          // 0..1 -> rows wm*128..+128
  const int wn = wave & 3;           // 0..3 -> cols wn*64..+64
  const int fr = lane & 15;
  const int fg = lane >> 4;          // 0..3

  // ---- staging constants (2 issues per thread per half-slab)
  const bf16* Aroot = (A2 && zb >= 4) ? A2 : A;
  const int   za    = (A2 && zb >= 4) ? zb - 4 : zb;
  const bf16* Abase = Aroot + (size_t)za * sAb + (size_t)m0 * K;
  const bf16* Bbase = B + (size_t)zb * sBb + (size_t)n0 * K;
  size_t gOff[2];
  int    ldsOff[2];
#pragma unroll
  for (int j = 0; j < 2; ++j) {
    const int L   = j * 8192 + t * 16;   // byte offset within 16KB slab-part
    const int row = L >> 6;              // 0..255
    const int gp  = (L >> 4) & 3;        // linear LDS granule
    const int g   = gp ^ ((row >> 1) & 3);   // pre-swizzled global granule
    gOff[j]   = (size_t)row * K + (size_t)g * 8;
    ldsOff[j] = j * 4096 + wave * 512;   // elements; wave-uniform; HW adds lane*16B
  }
  const int HMAX = (K >> 5) * 2;   // 2 half-slabs per 32-wide slab

  auto stage = [&](int H) {
    if (H >= HMAX) return;
    const int sl   = H >> 1;
    const int slot = sl & 3;
    const size_t kof = (size_t)sl * 32;
    if ((H & 1) == 0) {
      gload16(Abase + kof + gOff[0], As + slot * 8192 + ldsOff[0]);
      gload16(Abase + kof + gOff[1], As + slot * 8192 + ldsOff[1]);
    } else {
      gload16(Bbase + kof + gOff[0], Bs + slot * 8192 + ldsOff[0]);
      gload16(Bbase + kof + gOff[1], Bs + slot * 8192 + ldsOff[1]);
    }
  };

  // ---- fragment read offsets (swizzled): row base multiple of 16 -> xor is (fr>>1)&3
  const int xsw  = (fg ^ ((fr >> 1) & 3)) * 8;
  const int aoff = (wm * 128 + fr) * 32 + xsw;
  const int boff = (wn * 64 + fr) * 32 + xsw;

  f32x4 acc[8][4] = {};
  const int T = K >> 6;   // K-tiles of 64

  // prologue: A(s0),B(s0),A(s1),B(s1),A(s2); need slab 0 (H<=1) -> vmcnt(6)
  stage(0); stage(1); stage(2); stage(3); stage(4);
  asm volatile("s_waitcnt vmcnt(6)" ::: "memory");
  __builtin_amdgcn_s_barrier();

  for (int tt = 0; tt < T; ++tt) {
#pragma unroll
    for (int p = 0; p < 4; ++p) {
      const int kk   = p & 1;        // k-half of this K-tile (32-slab)
      const int oh   = p >> 1;       // output half (mi 0-3 / 4-7)
      const int slot = (2 * tt + kk) & 3;
      bf16x8 af[4], bfv[4];
#pragma unroll
      for (int i2 = 0; i2 < 4; ++i2)
        af[i2]  = *(const bf16x8*)(As + slot * 8192 + aoff + (oh * 4 + i2) * 512);
#pragma unroll
      for (int i2 = 0; i2 < 4; ++i2)
        bfv[i2] = *(const bf16x8*)(Bs + slot * 8192 + boff + i2 * 512);
      stage(4 * tt + p + 5);         // one half-slab, 5 phases ahead of first use
      __builtin_amdgcn_s_barrier();
      __builtin_amdgcn_s_setprio(1);
#pragma unroll
      for (int mi = 0; mi < 4; ++mi)
#pragma unroll
        for (int ni = 0; ni < 4; ++ni)
          acc[oh * 4 + mi][ni] =
            __builtin_amdgcn_mfma_f32_16x16x32_bf16(af[mi], bfv[ni], acc[oh * 4 + mi][ni], 0, 0, 0);
      __builtin_amdgcn_s_setprio(0);
      if constexpr (PV_ATTN) {
        // emit f32 attn rows from the A-fragments (this block's K-quarter only)
        if (wn == 0 && n_tile == (tt >> 3)) {
          const int sl = 2 * tt + kk;
          float* fb = attnF + (size_t)zb * sFb
                    + (size_t)(m0 + wm * 128) * 2048 + sl * 32 + fg * 8;
#pragma unroll
          for (int i2 = 0; i2 < 4; ++i2) {
            const int rloc = (oh * 4 + i2) * 16 + fr;
            f32x4 lo, hi;
#pragma unroll
            for (int e = 0; e < 4; ++e) { lo[e] = (float)af[i2][e]; hi[e] = (float)af[i2][4 + e]; }
            __builtin_nontemporal_store(lo, (f32x4*)(fb + (size_t)rloc * 2048));
            __builtin_nontemporal_store(hi, (f32x4*)(fb + (size_t)rloc * 2048 + 4));
          }
        }
      }
      if (p == 0) {                   // publish slab 2tt+1 for p1 reads
        if (tt == T - 1) asm volatile("s_waitcnt vmcnt(0)" ::: "memory");
        else             asm volatile("s_waitcnt vmcnt(4)" ::: "memory");
      }
      if (p == 3) {                   // publish slab 2tt+2 for next tile's p0 reads
        if (tt < T - 2)       asm volatile("s_waitcnt vmcnt(6)" ::: "memory");
        else if (tt == T - 2) asm volatile("s_waitcnt vmcnt(4)" ::: "memory");
      }
      __builtin_amdgcn_s_barrier();
    }
  }

  // ---- epilogue: per-wave 16KB LDS repack, 16B-chunk XOR swizzle.
  bf16* wbuf = (bf16*)(smem + wave * 16384);   // [128 rows][128 bytes]
#pragma unroll
  for (int mi = 0; mi < 8; ++mi) {
#pragma unroll
    for (int ni = 0; ni < 4; ++ni) {
      const int col = n0 + wn * 64 + ni * 16 + fr;
#pragma unroll
      for (int i2 = 0; i2 < 4; ++i2) {
        const int r = mi * 16 + fg * 4 + i2;    // local row 0..127
        float v = acc[mi][ni][i2] * scale;
        if constexpr (BIAS_MODE == 1) v += bp[col];
        if constexpr (BIAS_MODE == 2) v += bp[m0 + wm * 128 + r];
        if constexpr (GELU) v = 0.5f * v * (1.0f + erff(v * 0.70710678118f));
        const int cb = ni * 32 + fr * 2;        // byte col 0..126
        *(bf16*)((char*)wbuf + r * 128 + (cb ^ ((r & 7) << 4))) = (bf16)v;
      }
    }
  }
  __syncthreads();   // repack writes visible before readback
  const int rowbase = m0 + wm * 128;
  const int colbase = n0 + wn * 64;
#pragma unroll
  for (int j = 0; j < 16; ++j) {
    const int r  = j * 8 + (lane >> 3);
    const int cg = lane & 7;                    // global 16B chunk within 128B row
    bf16x8 val = *(const bf16x8*)((char*)wbuf + r * 128 + ((cg << 4) ^ ((r & 7) << 4)));
    *(bf16x8*)(Cout + (size_t)zb * sCb + (size_t)(rowbase + r) * ldc + colbase + cg * 8) = val;
  }
}

// ---------------- pre1: z=0 weight transpose (all 4 via x>>8); z=1 conv Q; z=2 conv K
__global__ __launch_bounds__(256)
void pre1_k(const float* __restrict__ W0, const float* __restrict__ W1,
            const float* __restrict__ W2, const float* __restrict__ W3,
            bf16* __restrict__ wts,
            const float* __restrict__ Q, const float* __restrict__ Kin,
            bf16* __restrict__ Qb, bf16* __restrict__ Kb, long n8)
{
  __shared__ __align__(16) char sb[64 * 72 * 2];
  const int t = threadIdx.x;
  if (blockIdx.z == 0) {
    const float* Ws[4] = {W0, W1, W2, W3};
    const int wsel = blockIdx.x >> 8;
    const float* W = Ws[wsel];
    bf16* o = wts + (size_t)wsel * (1024 * 1024);
    const int c0 = (blockIdx.x & 15) * 64;
    const int r0 = ((blockIdx.x >> 4) & 15) * 64;
    bf16 (*tile)[72] = (bf16(*)[72])sb;
    {
      const int rr = t >> 2;
      const int cc = (t & 3) * 16;
      const float* src = W + (size_t)(r0 + rr) * 1024 + c0 + cc;
#pragma unroll
      for (int j = 0; j < 16; j += 4) {
        f32x4 v = __builtin_nontemporal_load((const f32x4*)(src + j));
#pragma unroll
        for (int i = 0; i < 4; ++i) tile[cc + j + i][rr] = (bf16)v[i];
      }
    }
    __syncthreads();
    {
      const int nr = t >> 2;
      const int kc = (t & 3) * 16;
      bf16* dst = o + (size_t)(c0 + nr) * 1024 + r0 + kc;
      *(bf16x8*)dst       = *(const bf16x8*)&tile[nr][kc];
      *(bf16x8*)(dst + 8) = *(const bf16x8*)&tile[nr][kc + 8];
    }
  } else {
    const float* in = (blockIdx.z == 1) ? Q : Kin;
    bf16* out = (blockIdx.z == 1) ? Qb : Kb;
    for (long i = blockIdx.x * 256 + t; i < n8; i += (long)gridDim.x * 256) {
      f32x4 a = __builtin_nontemporal_load((const f32x4*)(in + i * 8));
      f32x4 b = __builtin_nontemporal_load((const f32x4*)(in + i * 8 + 4));
      bf16x8 o;
#pragma unroll
      for (int j = 0; j < 4; ++j) { o[j] = (bf16)a[j]; o[4 + j] = (bf16)b[j]; }
      *(bf16x8*)(out + i * 8) = o;
    }
  }
}

// ---------------- pre2: z<8 mask transpose+BITPACK batch z; z=8 conv V
// (separate dispatch AFTER projections: mTb overwrites Qb, Vb overwrites Kb)
__global__ __launch_bounds__(256)
void pre2_k(const unsigned int* __restrict__ mask, unsigned char* __restrict__ mTb,
            const float* __restrict__ V, bf16* __restrict__ Vb, long n8)
{
  __shared__ __align__(16) char sb[64 * 72 * 2];
  const int t = threadIdx.x;
  if (blockIdx.z < 8) {
    const int b  = blockIdx.z;
    const int k0 = (blockIdx.x & 31) * 64;
    const int q0 = (blockIdx.x >> 5) * 64;
    signed char (*tile)[65] = (signed char(*)[65])sb;
    {
      const int iq = t >> 2;
      const int ic = (t & 3) * 16;
      const unsigned int* src = mask + ((size_t)b * 2048 + q0 + iq) * 2048 + k0 + ic;
#pragma unroll
      for (int j = 0; j < 16; j += 4) {
        u32x4 v = __builtin_nontemporal_load((const u32x4*)(src + j));
#pragma unroll
        for (int i = 0; i < 4; ++i) tile[ic + j + i][iq] = (signed char)v[i];
      }
    }
    __syncthreads();
    {
      const int ik = t >> 2;             // k within tile 0..63
      const int iq = (t & 3) * 16;       // q start 0/16/32/48
      unsigned int bits = 0;
#pragma unroll
      for (int j = 0; j < 16; ++j) bits |= (unsigned int)(tile[ik][iq + j] & 1) << j;
      *(unsigned short*)(mTb + ((size_t)b * 2048 + k0 + ik) * 256 + ((q0 + iq) >> 3)) =
          (unsigned short)bits;
    }
  } else {
    for (long i = blockIdx.x * 256 + t; i < n8; i += (long)gridDim.x * 256) {
      f32x4 a = __builtin_nontemporal_load((const f32x4*)(V + i * 8));
      f32x4 b = __builtin_nontemporal_load((const f32x4*)(V + i * 8 + 4));
      bf16x8 o;
#pragma unroll
      for (int j = 0; j < 4; ++j) { o[j] = (bf16)a[j]; o[4 + j] = (bf16)b[j]; }
      *(bf16x8*)(Vb + i * 8) = o;
    }
  }
}

// ---------------- row softmax, XCD-pinned: block i -> batch i%8, row i/8.
// Reads bf16 scores (first 4KB of 8KB row slot) + bitpacked mask; writes ONLY
// bf16 attnb (normal stores -> stays in XCD L2 for PV). The f32 attn output is
// emitted later by the PV GEMM as an upcast of attnb (error ~2^-9 << 0.1 thr).
__global__ __launch_bounds__(256)
void softmax_rows_k(float* __restrict__ P, const unsigned char* __restrict__ mTb,
                    bf16* __restrict__ Pb0, bf16* __restrict__ Pb1)
{
  const int b  = blockIdx.x & 7;
  const int rw = blockIdx.x >> 3;
  const size_t r = (size_t)b * 2048 + rw;
  const bf16* pin = (const bf16*)((const char*)P + r * 8192);
  bf16* pb = (b < 4) ? (Pb0 + ((size_t)b * 2048 + rw) * 2048)
                     : (Pb1 + ((size_t)(b - 4) * 2048 + rw) * 2048);
  const int t = threadIdx.x;
  const int wave = t >> 6, lane = t & 63;
  bf16x8 raw = *(const bf16x8*)(pin + t * 8);
  const unsigned int mbyte = mTb[r * 256 + t];   // 8 q-bits for this thread
  float v[8];
#pragma unroll
  for (int j = 0; j < 8; ++j)
    v[j] = (float)raw[j] + (((mbyte >> j) & 1) ? -1e9f : 0.0f);
  float m = -3e38f;
#pragma unroll
  for (int j = 0; j < 8; ++j) m = fmaxf(m, v[j]);
#pragma unroll
  for (int off = 32; off; off >>= 1) m = fmaxf(m, __shfl_xor(m, off));
  __shared__ float red[8];
  if (lane == 0) red[wave] = m;
  __syncthreads();
  m = fmaxf(fmaxf(red[0], red[1]), fmaxf(red[2], red[3]));
  float s = 0.0f;
#pragma unroll
  for (int j = 0; j < 8; ++j) { v[j] = __expf(v[j] - m); s += v[j]; }
#pragma unroll
  for (int off = 32; off; off >>= 1) s += __shfl_xor(s, off);
  if (lane == 0) red[4 + wave] = s;
  __syncthreads();
  s = red[4] + red[5] + red[6] + red[7];
  const float inv = 1.0f / s;
  bf16x8 ob;
#pragma unroll
  for (int j = 0; j < 8; ++j) ob[j] = (bf16)(v[j] * inv);
  *(bf16x8*)(pb + t * 8) = ob;
}

// ---------------- LayerNorm over 1024, bf16 input, XCD-pinned (block i -> row
// (i%8)*2048 + i/8, matching gelu's batch->XCD placement for warm g reads).
__global__ __launch_bounds__(256)
void ln_k(const bf16* __restrict__ g, const float* __restrict__ gamma,
          const float* __restrict__ beta, float* __restrict__ out)
{
  const size_t r = (size_t)(blockIdx.x & 7) * 2048 + (blockIdx.x >> 3);
  const bf16* p = g + r * 1024;
  const int t = threadIdx.x;
  const int wave = t >> 6, lane = t & 63;
  bf16x4 raw = *(const bf16x4*)(p + t * 4);
  f32x4 v;
#pragma unroll
  for (int j = 0; j < 4; ++j) v[j] = (float)raw[j];
  float s = v[0] + v[1] + v[2] + v[3];
  float q = v[0]*v[0] + v[1]*v[1] + v[2]*v[2] + v[3]*v[3];
#pragma unroll
  for (int off = 32; off; off >>= 1) { s += __shfl_xor(s, off); q += __shfl_xor(q, off); }
  __shared__ float red[16];
  if (lane == 0) { red[wave] = s; red[8 + wave] = q; }
  __syncthreads();
  s = red[0] + red[1] + red[2] + red[3];
  q = red[8] + red[9] + red[10] + red[11];
  const float mu   = s * (1.0f / 1024.0f);
  const float var  = q * (1.0f / 1024.0f) - mu * mu;
  const float rstd = rsqrtf(var + 1e-5f);
  f32x4 gm = *(const f32x4*)(gamma + t * 4);
  f32x4 bt = *(const f32x4*)(beta + t * 4);
  f32x4 o;
#pragma unroll
  for (int j = 0; j < 4; ++j) o[j] = (v[j] - mu) * rstd * gm[j] + bt[j];
  __builtin_nontemporal_store(o, (f32x4*)(out + r * 1024 + t * 4));
}

extern "C" void kernel_launch(void* const* d_in, const int* in_sizes, int n_in,
                              void* d_out, int out_size, void* d_ws, size_t ws_size,
                              hipStream_t stream)
{
  const float* Q     = (const float*)d_in[0];
  const float* Kin   = (const float*)d_in[1];
  const float* V     = (const float*)d_in[2];
  const unsigned int* mask = (const unsigned int*)d_in[3];
  const float* Wq    = (const float*)d_in[4];
  const float* bq    = (const float*)d_in[5];
  const float* Wk    = (const float*)d_in[6];
  const float* bk    = (const float*)d_in[7];
  const float* Wv    = (const float*)d_in[8];
  const float* bv    = (const float*)d_in[9];
  const float* Wo    = (const float*)d_in[10];
  const float* bo    = (const float*)d_in[11];
  const float* gamma = (const float*)d_in[12];
  const float* beta  = (const float*)d_in[13];

  float* outCtx  = (float*)d_out;                      // [8,2048,1024]
  float* outAttn = outCtx + (size_t)8 * 2048 * 1024;   // [8,2048,2048] f32 (k,q); 8KB rows

  // workspace (MiB offsets), peak 136 MiB; per-region timeline:
  // [0,8)    wts (whole run)
  // [8,40)   qp (proj->QKT)   -> wvT (wvT->PV)
  // [40,72)  kp (proj->QKT)   -> attnb b0-3 (softmax->PV) -> g (gelu->ln)
  // [72,104) Qb (pre1->proj)  -> mTb 4MB (pre2->softmax)  -> ctx (PV->gelu)
  // [104,136) Kb (pre1->proj) -> Vb (pre2->wvT)           -> attnb b4-7 (softmax->PV)
  char* ws = (char*)d_ws;
  const size_t MB = 1048576;
  bf16*          wts   = (bf16*)(ws + 0 * MB);
  bf16*          qp    = (bf16*)(ws + 8 * MB);
  bf16*          kp    = (bf16*)(ws + 40 * MB);
  bf16*          Qb    = (bf16*)(ws + 72 * MB);
  bf16*          Kb    = (bf16*)(ws + 104 * MB);
  unsigned char* mTb   = (unsigned char*)(ws + 72 * MB);
  bf16*          Vb    = (bf16*)(ws + 104 * MB);
  bf16*          wvT   = (bf16*)(ws + 8 * MB);
  bf16*          attnb0= (bf16*)(ws + 40 * MB);
  bf16*          attnb1= (bf16*)(ws + 104 * MB);
  bf16*          ctx   = (bf16*)(ws + 72 * MB);
  bf16*          g     = (bf16*)(ws + 40 * MB);
  bf16* Wvt = wts + 2 * 1024 * 1024;
  bf16* Wot = wts + 3 * 1024 * 1024;

  const dim3 blk(256);
  const dim3 blk8(512);
  const long n8 = (long)16384 * 1024 / 8;

  // 1. pre1: weights->bf16 transposed (z=0), Q->bf16 (z=1), K->bf16 (z=2)
  pre1_k<<<dim3(1024, 1, 3), blk, 0, stream>>>(Wq, Wk, Wv, Wo, wts, Q, Kin, Qb, Kb, n8);
  // 2. merged projections (512 blocks): XCD c -> z=c>>2, m-chunk c&3 (16 tiles), 4 n-tiles
  bgemm8_k<1, false, false><<<dim3(512), blk8, 0, stream>>>(
      Qb, nullptr, wts, bq, bk, qp, 1024, 1024,
      16777216, 1048576, 16777216, 1.0f, 2, 2, 16, nullptr, 0);
  // 3. pre2 (AFTER projections — mTb/Vb overwrite Qb/Kb): mask bitpack (z<8), V (z=8)
  pre2_k<<<dim3(1024, 1, 9), blk, 0, stream>>>(mask, mTb, V, Vb, n8);
  // 4. QKT (512 blocks): XCD c -> batch c; 8x8 tiles; scores bf16 (ldc=4096)
  bgemm8_k<0, false, false><<<dim3(512), blk8, 0, stream>>>(
      kp, nullptr, qp, nullptr, nullptr, (bf16*)outAttn, 4096, 1024,
      (long)2048 * 1024, (long)2048 * 1024, (long)2048 * 4096, 0.03125f, 3, 0, 8, nullptr, 0);
  // 5. wvT (256 blocks): XCD c -> batch c; 4 m-tiles x 8 n-tiles
  bgemm8_k<2, false, false><<<dim3(256), blk8, 0, stream>>>(
      Wvt, nullptr, Vb, bv, nullptr, wvT, 2048, 1024,
      0, (long)2048 * 1024, (long)1024 * 2048, 1.0f, 3, 0, 4, nullptr, 0);
  // 6. softmax (XCD-pinned rows): scores + mask bits -> bf16 attnb ONLY
  softmax_rows_k<<<dim3(16384), blk, 0, stream>>>(outAttn, mTb, attnb0, attnb1);
  // 7. PV (256 blocks): XCD c -> batch c; 8 m-tiles x 4 n-tiles.
  //    Also emits the f32 attn output (upcast of attnb fragments, NT stores).
  bgemm8_k<0, false, true><<<dim3(256), blk8, 0, stream>>>(
      attnb0, attnb1, wvT, nullptr, nullptr, ctx, 1024, 2048,
      (long)2048 * 2048, (long)1024 * 2048, (long)2048 * 1024, 1.0f, 2, 0, 8,
      outAttn, (long)2048 * 2048);
  // 8. gelu (256 blocks): XCD c -> m-chunk c (= batch c rows), 4 n-tiles
  bgemm8_k<1, true, false><<<dim3(256), blk8, 0, stream>>>(
      ctx, nullptr, Wot, bo, nullptr, g, 1024, 1024,
      0, 0, 0, 1.0f, 2, 3, 8, nullptr, 0);
  // 9. LayerNorm (XCD-pinned rows) -> context output
  ln_k<<<dim3(16384), blk, 0, stream>>>(g, gamma, beta, outCtx);
}